// Round 4
// baseline (266.289 us; speedup 1.0000x reference)
//
#include <hip/hip_runtime.h>

typedef short bfx8 __attribute__((ext_vector_type(8)));
typedef float fx4 __attribute__((ext_vector_type(4)));

#define D 256
#define E_TILE 64

__device__ __forceinline__ float b2f(short s) {
  union { unsigned u; float f; } v; v.u = ((unsigned)(unsigned short)s) << 16; return v.f;
}
__device__ __forceinline__ short f2b(float f) {
  union { float f; unsigned u; } v; v.f = f;
  unsigned u = v.u;
  u += 0x7fffu + ((u >> 16) & 1u);   // RNE
  return (short)(u >> 16);
}
__device__ __forceinline__ float relu(float f) { return f > 0.f ? f : 0.f; }

// ---------------- prep: convert weights to bf16 in ws ----------------
// B1[n][k], n in [0,512): n<256 -> W1[n][k] (P part); n>=256 -> W1[n-256][256+k] (Q part)
__global__ void k_prep(const float* __restrict__ W1, const float* __restrict__ W2,
                       unsigned short* __restrict__ B1, unsigned short* __restrict__ W2b) {
  int t = blockIdx.x * 256 + threadIdx.x;
  if (t < 512 * 256) {
    int n = t >> 8, k = t & 255;
    float v = (n < 256) ? W1[n * 512 + k] : W1[(n - 256) * 512 + 256 + k];
    B1[t] = (unsigned short)f2b(v);
  } else if (t < 512 * 256 + 256 * 256) {
    int i = t - 512 * 256;
    W2b[i] = (unsigned short)f2b(W2[i]);
  }
}

// ---------------- node kernel: PQ[m][0:512] = x[m] @ B1^T (bf16 out) ----------------
// block: 256 thr (4 waves). Tile 64M x 512N, K=256 in 8 chunks of 32.
// wave w owns N range [w*128, w*128+128).
// b1 is FOLDED into the P half here (n<256): PQ[m][n] = x[m].W1[n] + b1[n],
// so k_edge's fuse is just relu(P+Q) — no smB1 read, no bias add per edge.
__launch_bounds__(256, 2)
__global__ void k_node(const float* __restrict__ x, const unsigned short* __restrict__ B1,
                       const float* __restrict__ b1,
                       unsigned short* __restrict__ PQ, int n_nodes) {
  __shared__ __align__(16) short smA[64 * 40];    // stride 40 (pad 8) -> 16B aligned rows
  __shared__ __align__(16) short smW[512 * 40];
  short* smT = smW;                               // [32][520] alias for store transpose
  const int tid = threadIdx.x;
  const int wave = tid >> 6, lane = tid & 63;
  const int lr = lane & 15, lg = lane >> 4;
  const int m0 = blockIdx.x * 64;

  // per-thread bias for the 8 n-tiles this wave owns (0 for the Q half)
  float b1v[8];
#pragma unroll
  for (int nt = 0; nt < 8; ++nt) {
    int n = wave * 128 + nt * 16 + lr;
    b1v[nt] = (n < 256) ? b1[n] : 0.f;
  }

  fx4 acc[4][8] = {};

#pragma unroll 1
  for (int ks = 0; ks < 8; ++ks) {
    const int k0 = ks * 32;
    // stage A chunk: 64 rows x 32 cols fp32 -> bf16
    {
      int r = tid >> 2, c = (tid & 3) * 8;
      int m = m0 + r;
      bfx8 o;
      if (m < n_nodes) {
        const float* p = x + (size_t)m * 256 + k0 + c;
        float4 v0 = *(const float4*)(p);
        float4 v1 = *(const float4*)(p + 4);
        o[0] = f2b(v0.x); o[1] = f2b(v0.y); o[2] = f2b(v0.z); o[3] = f2b(v0.w);
        o[4] = f2b(v1.x); o[5] = f2b(v1.y); o[6] = f2b(v1.z); o[7] = f2b(v1.w);
      } else {
        o = (bfx8){0,0,0,0,0,0,0,0};
      }
      *(bfx8*)&smA[r * 40 + c] = o;
    }
    // stage W chunk: 512 rows x 32 cols bf16
#pragma unroll
    for (int it = 0; it < 8; ++it) {
      int idx = it * 256 + tid;
      int n = idx >> 2, c = (idx & 3) * 8;
      bfx8 v = *(const bfx8*)(B1 + n * 256 + k0 + c);
      *(bfx8*)&smW[n * 40 + c] = v;
    }
    __syncthreads();
    bfx8 af[4];
#pragma unroll
    for (int mt = 0; mt < 4; ++mt)
      af[mt] = *(const bfx8*)&smA[(mt * 16 + lr) * 40 + lg * 8];
#pragma unroll
    for (int nt = 0; nt < 8; ++nt) {
      int n = wave * 128 + nt * 16 + lr;
      bfx8 bf = *(const bfx8*)&smW[n * 40 + lg * 8];
#pragma unroll
      for (int mt = 0; mt < 4; ++mt)
        acc[mt][nt] = __builtin_amdgcn_mfma_f32_16x16x32_bf16(af[mt], bf, acc[mt][nt], 0, 0, 0);
    }
    __syncthreads();
  }

  // epilogue: two half-passes through smT for coalesced bf16 stores.
  // FULLY unrolled (h compile-time) so acc[] stays statically indexed ->
  // registers, not scratch. (An earlier `#pragma unroll 1` here made mt
  // runtime-dependent, spilling the 128-float acc to scratch: 1.6 GB of
  // HBM traffic, k_node 385us.)
#pragma unroll
  for (int h = 0; h < 2; ++h) {
#pragma unroll
    for (int mt2 = 0; mt2 < 2; ++mt2) {
      const int mt = 2 * h + mt2;
#pragma unroll
      for (int nt = 0; nt < 8; ++nt)
#pragma unroll
        for (int i = 0; i < 4; ++i) {
          int mrow = mt2 * 16 + lg * 4 + i;
          int n = wave * 128 + nt * 16 + lr;
          smT[mrow * 520 + n] = f2b(acc[mt][nt][i] + b1v[nt]);
        }
    }
    __syncthreads();
    int r = tid >> 3, cbase = (tid & 7) * 8;
    int m = m0 + h * 32 + r;
    if (m < n_nodes) {
#pragma unroll
      for (int j = 0; j < 8; ++j) {
        int c = cbase + j * 64;
        *(bfx8*)(PQ + (size_t)m * 512 + c) = *(const bfx8*)&smT[r * 520 + c];
      }
    }
    __syncthreads();
  }
}

// ---------------- edge kernel: h1=relu(P[src]+Q[dst]); h2=relu(h1@W2^T+b2); out=h2@w3+b3 --
// persistent, 4 waves/block; wave w owns n in [w*64, w*64+64); W2 frags live in registers.
//
// OCCUPANCY MODEL (round-3 finding): arch regs = VGPR(128) + AGPRs > 128 ->
// 129..256 bucket -> 2 waves/SIMD -> 2 blocks/CU, REGARDLESS of grid size
// (grid 512 and 1024 both measured ~20.5% occupancy, ~92-97us). bw[4][8]
// alone is 128 VGPRs, so 4 blocks/CU is structurally unreachable. Instead we
// exploit the ~100 FREE regs in the 256 bucket for a T14-style pipeline:
//   - smH double-buffered (2x33.8KB; 68.6KB/block x2 blocks = 137KB <= 160KB)
//   - tile t+G's PQ rows prefetched into regs (pv/qv, 64 VGPRs) ISSUED BEFORE
//     the GEMM, so the ~900cy gather latency hides under MFMA+epilogue
//   - indices prefetched 2 tiles ahead (no waitcnt before the row issues)
// DO NOT tighten __launch_bounds__ past (256,2): (256,4) forced VGPR=64 and
// spilled bw[] (WRITE_SIZE 7.3->137MB, 92->180us). If WRITE_SIZE jumps above
// ~15MB here, the prefetch regs spilled -> shrink pv/qv prefetch.
__launch_bounds__(256, 2)
__global__ void k_edge(const unsigned short* __restrict__ PQ,
                       const int* __restrict__ src, const int* __restrict__ dst,
                       const unsigned short* __restrict__ W2b,
                       const float* __restrict__ b2, const float* __restrict__ W3,
                       const float* __restrict__ b3, float* __restrict__ out,
                       int E, int ntiles) {
  __shared__ __align__(16) short smH[2 * 64 * 264]; // double-buffered, stride 264 (pad 8)
  __shared__ float smS[4][64];
  const int tid = threadIdx.x;
  const int wave = tid >> 6, lane = tid & 63;
  const int lr = lane & 15, lg = lane >> 4;
  const int G = gridDim.x;

  // W2 fragments (this wave's 64 N rows, full K=256): 4 n-tiles x 8 k-steps
  bfx8 bw[4][8];
  float b2v[4], w3v[4];
#pragma unroll
  for (int nt = 0; nt < 4; ++nt) {
    int n = wave * 64 + nt * 16 + lr;
    b2v[nt] = b2[n];
    w3v[nt] = W3[n];
#pragma unroll
    for (int ks = 0; ks < 8; ++ks)
      bw[nt][ks] = *(const bfx8*)(W2b + n * 256 + ks * 32 + lg * 8);
  }
  const float b3v = b3[0];

  // gather role: r = edge row within tile (4 threads/edge), cb = col sub-block
  const int r = tid >> 2, cb = (tid & 3) * 8;
  const int t0 = blockIdx.x;

  bfx8 pv[8], qv[8];   // prefetched raw P/Q rows for the tile about to be fused
  int sN, dN;          // prefetched indices for the tile AFTER that

  // pipeline prologue: rows(t0) + idx(t0+G)
  {
    int e = t0 * E_TILE + r; if (e >= E) e = 0;   // clamp: row never stored
    int s0 = src[e], d0 = dst[e];
    const unsigned short* ps = PQ + (size_t)s0 * 512;
    const unsigned short* pd = PQ + (size_t)d0 * 512 + 256;
#pragma unroll
    for (int it = 0; it < 8; ++it) {
      int c = cb + it * 32;
      pv[it] = *(const bfx8*)(ps + c);
      qv[it] = *(const bfx8*)(pd + c);
    }
    int e2 = (t0 + G) * E_TILE + r; if (e2 >= E) e2 = 0;
    sN = src[e2]; dN = dst[e2];
  }

  int buf = 0;
  for (int t = t0; t < ntiles; t += G) {
    short* Hb = &smH[buf * (64 * 264)];
    // fuse layer1 from prefetched regs: h1 = relu(P'+Q)  (b1 already in P')
#pragma unroll
    for (int it = 0; it < 8; ++it) {
      int c = cb + it * 32;
      bfx8 o;
#pragma unroll
      for (int j = 0; j < 8; ++j)
        o[j] = f2b(relu(b2f(pv[it][j]) + b2f(qv[it][j])));
      *(bfx8*)&Hb[r * 264 + c] = o;
    }
    __syncthreads();

    // issue next tile's gather NOW; latency hides under the GEMM below
    if (t + G < ntiles) {
      const unsigned short* ps = PQ + (size_t)sN * 512;
      const unsigned short* pd = PQ + (size_t)dN * 512 + 256;
#pragma unroll
      for (int it = 0; it < 8; ++it) {
        int c = cb + it * 32;
        pv[it] = *(const bfx8*)(ps + c);
        qv[it] = *(const bfx8*)(pd + c);
      }
      int e2 = (t + 2 * G) * E_TILE + r; if (e2 >= E) e2 = 0;
      sN = src[e2]; dN = dst[e2];
    }

    // layer2 GEMM: 64M x 64N per wave, K=256
    fx4 acc[4][4] = {};
#pragma unroll
    for (int ks = 0; ks < 8; ++ks) {
      bfx8 af[4];
#pragma unroll
      for (int mt = 0; mt < 4; ++mt)
        af[mt] = *(const bfx8*)&Hb[(mt * 16 + lr) * 264 + ks * 32 + lg * 8];
#pragma unroll
      for (int nt = 0; nt < 4; ++nt)
#pragma unroll
        for (int mt = 0; mt < 4; ++mt)
          acc[mt][nt] = __builtin_amdgcn_mfma_f32_16x16x32_bf16(af[mt], bw[nt][ks], acc[mt][nt], 0, 0, 0);
    }

    // epilogue: relu(acc+b2) dot w3, reduce over this wave's 64 n via shfl within 16-groups
#pragma unroll
    for (int mt = 0; mt < 4; ++mt)
#pragma unroll
      for (int i = 0; i < 4; ++i) {
        float p = 0.f;
#pragma unroll
        for (int nt = 0; nt < 4; ++nt)
          p += relu(acc[mt][nt][i] + b2v[nt]) * w3v[nt];
        p += __shfl_xor(p, 1);
        p += __shfl_xor(p, 2);
        p += __shfl_xor(p, 4);
        p += __shfl_xor(p, 8);
        if (lr == 0) smS[wave][mt * 16 + lg * 4 + i] = p;
      }
    __syncthreads();
    if (tid < 64) {
      int e = t * E_TILE + tid;
      if (e < E) out[e] = smS[0][tid] + smS[1][tid] + smS[2][tid] + smS[3][tid] + b3v;
    }
    // no trailing sync: next iter's post-fuse __syncthreads() orders smS reuse,
    // and the fuse writes the OTHER smH buffer.
    buf ^= 1;
  }
}

// ---------------- fallback (if ws too small): naive fp32, 1 edge per wave ----------------
__global__ void k_fallback(const float* __restrict__ x, const int* __restrict__ src,
                           const int* __restrict__ dst, const float* __restrict__ W1,
                           const float* __restrict__ b1, const float* __restrict__ W2,
                           const float* __restrict__ b2, const float* __restrict__ W3,
                           const float* __restrict__ b3, float* __restrict__ out, int E) {
  __shared__ float smF[4][512];
  __shared__ float smG[4][256];
  int wave = threadIdx.x >> 6, lane = threadIdx.x & 63;
  int e = blockIdx.x * 4 + wave;
  bool valid = e < E;
  int ec = valid ? e : 0;
  int s = src[ec], d = dst[ec];
  for (int j = 0; j < 8; ++j) {
    int k = lane * 8 + j;
    smF[wave][k] = (k < 256) ? x[(size_t)s * 256 + k] : x[(size_t)d * 256 + k - 256];
  }
  __syncthreads();
  for (int t = 0; t < 4; ++t) {
    int n = lane + t * 64;
    float a = b1[n];
    for (int k = 0; k < 512; ++k) a += smF[wave][k] * W1[n * 512 + k];
    smG[wave][n] = relu(a);
  }
  __syncthreads();
  float p = 0.f;
  for (int t = 0; t < 4; ++t) {
    int n = lane + t * 64;
    float a = b2[n];
    for (int k = 0; k < 256; ++k) a += smG[wave][k] * W2[n * 256 + k];
    p += relu(a) * W3[n];
  }
  for (int m = 1; m < 64; m <<= 1) p += __shfl_xor(p, m);
  if (lane == 0 && valid) out[e] = p + b3[0];
}

extern "C" void kernel_launch(void* const* d_in, const int* in_sizes, int n_in,
                              void* d_out, int out_size, void* d_ws, size_t ws_size,
                              hipStream_t stream) {
  const float* x  = (const float*)d_in[0];
  const int*   src = (const int*)d_in[1];
  const int*   dst = (const int*)d_in[2];
  const float* W1 = (const float*)d_in[3];
  const float* b1 = (const float*)d_in[4];
  const float* W2 = (const float*)d_in[5];
  const float* b2 = (const float*)d_in[6];
  const float* W3 = (const float*)d_in[7];
  const float* b3 = (const float*)d_in[8];
  float* out = (float*)d_out;

  const int E = in_sizes[1];
  const int n_nodes = in_sizes[0] / 256;

  const size_t offB1 = 0;
  const size_t offW2 = (size_t)512 * 256 * 2;                 // 262144
  const size_t offPQ = offW2 + (size_t)256 * 256 * 2;         // 393216
  const size_t need = offPQ + (size_t)n_nodes * 512 * 2;      // ~51.6 MB

  if (ws_size >= need) {
    unsigned short* B1  = (unsigned short*)((char*)d_ws + offB1);
    unsigned short* W2b = (unsigned short*)((char*)d_ws + offW2);
    unsigned short* PQ  = (unsigned short*)((char*)d_ws + offPQ);
    k_prep<<<768, 256, 0, stream>>>(W1, W2, B1, W2b);
    k_node<<<(n_nodes + 63) / 64, 256, 0, stream>>>(x, B1, b1, PQ, n_nodes);
    const int ntiles = (E + E_TILE - 1) / E_TILE;
    k_edge<<<512, 256, 0, stream>>>(PQ, src, dst, W2b, b2, W3, b3, out, E, ntiles);
  } else {
    k_fallback<<<(E + 3) / 4, 256, 0, stream>>>(x, src, dst, W1, b1, W2, b2, W3, b3, out, E);
  }
}

// Round 7
// 209.488 us; speedup vs baseline: 1.2711x; 1.2711x over previous
//
#include <hip/hip_runtime.h>

typedef short bfx8 __attribute__((ext_vector_type(8)));
typedef float fx4 __attribute__((ext_vector_type(4)));

#define D 256
#define E_TILE 64

__device__ __forceinline__ float b2f(short s) {
  union { unsigned u; float f; } v; v.u = ((unsigned)(unsigned short)s) << 16; return v.f;
}
__device__ __forceinline__ short f2b(float f) {
  union { float f; unsigned u; } v; v.f = f;
  unsigned u = v.u;
  u += 0x7fffu + ((u >> 16) & 1u);   // RNE
  return (short)(u >> 16);
}
__device__ __forceinline__ float relu(float f) { return f > 0.f ? f : 0.f; }

// ---------------- prep: convert weights to bf16 in ws ----------------
// B1[n][k], n in [0,512): n<256 -> W1[n][k] (P part); n>=256 -> W1[n-256][256+k] (Q part)
__global__ void k_prep(const float* __restrict__ W1, const float* __restrict__ W2,
                       unsigned short* __restrict__ B1, unsigned short* __restrict__ W2b) {
  int t = blockIdx.x * 256 + threadIdx.x;
  if (t < 512 * 256) {
    int n = t >> 8, k = t & 255;
    float v = (n < 256) ? W1[n * 512 + k] : W1[(n - 256) * 512 + 256 + k];
    B1[t] = (unsigned short)f2b(v);
  } else if (t < 512 * 256 + 256 * 256) {
    int i = t - 512 * 256;
    W2b[i] = (unsigned short)f2b(W2[i]);
  }
}

// ---------------- node kernel v2: PQ[m][0:512] = x[m] @ B1^T + [b1;0]  (bf16 out) -------
// ROUND-5 REWRITE. Old k_node re-staged ALL of B1 (256KB) through LDS in every
// one of 782 blocks (9 global loads + 9 ds_writes per thread per 32-K step,
// 16 barriers/tile) -> ~100us, 6x off the ~16us memory floor. New structure =
// the k_edge recipe: persistent 512-thr (8-wave) blocks, each wave owns 64 of
// the 512 N rows with B1 fragments IN REGISTERS (bw[4][8] = 128 VGPRs, the
// same proven-fitting budget as k_edge's W2). Per M-tile: stage 64x256 x-tile
// into LDS once (coalesced float4), 1 barrier, 128 MFMA/wave, transpose
// epilogue via aliased smT, coalesced stores. b1 folded into the P half.
__launch_bounds__(512, 1)
__global__ void k_node(const float* __restrict__ x, const unsigned short* __restrict__ B1,
                       const float* __restrict__ b1,
                       unsigned short* __restrict__ PQ, int n_nodes, int ntiles) {
  __shared__ __align__(16) short smA[64 * 264];   // 33.8 KB, stride 264 (pad 8)
  short* smT = smA;                               // [32][520] alias for store transpose
  const int tid = threadIdx.x;
  const int wave = tid >> 6, lane = tid & 63;
  const int lr = lane & 15, lg = lane >> 4;

  // B1 fragments: this wave's 64 N rows, full K=256 (128 VGPRs). Loaded once.
  bfx8 bw[4][8];
  float b1v[4];
#pragma unroll
  for (int nt = 0; nt < 4; ++nt) {
    int n = wave * 64 + nt * 16 + lr;
    b1v[nt] = (n < 256) ? b1[n] : 0.f;
#pragma unroll
    for (int ks = 0; ks < 8; ++ks)
      bw[nt][ks] = *(const bfx8*)(B1 + n * 256 + ks * 32 + lg * 8);
  }

  const int r  = tid >> 3;            // stage row 0..63
  const int c4 = (tid & 7) * 4;       // stage col base (floats); 8 lanes cover 32 contiguous floats
  const int rs = tid >> 4;            // store row 0..31
  const int cs = (tid & 15) * 8;      // store col base (shorts); 16 lanes cover 128 contiguous shorts

  for (int tile = blockIdx.x; tile < ntiles; tile += gridDim.x) {
    const int m0 = tile * 64;
    // ---- stage x-tile: 64 x 256 fp32 -> bf16, perfectly coalesced float4 loads ----
    {
      int m = m0 + r;
      if (m < n_nodes) {
        const float* p = x + (size_t)m * 256 + c4;
#pragma unroll
        for (int j = 0; j < 8; ++j) {
          float4 v = *(const float4*)(p + j * 32);
          short4 o = { f2b(v.x), f2b(v.y), f2b(v.z), f2b(v.w) };
          *(short4*)&smA[r * 264 + c4 + j * 32] = o;
        }
      } else {
        short4 z = {0, 0, 0, 0};
#pragma unroll
        for (int j = 0; j < 8; ++j)
          *(short4*)&smA[r * 264 + c4 + j * 32] = z;
      }
    }
    __syncthreads();

    // ---- GEMM: 64M x 64N per wave, K=256, B1 from registers ----
    fx4 acc[4][4] = {};
#pragma unroll
    for (int ks = 0; ks < 8; ++ks) {
      bfx8 af[4];
#pragma unroll
      for (int mt = 0; mt < 4; ++mt)
        af[mt] = *(const bfx8*)&smA[(mt * 16 + lr) * 264 + ks * 32 + lg * 8];
#pragma unroll
      for (int nt = 0; nt < 4; ++nt)
#pragma unroll
        for (int mt = 0; mt < 4; ++mt)
          acc[mt][nt] = __builtin_amdgcn_mfma_f32_16x16x32_bf16(af[mt], bw[nt][ks], acc[mt][nt], 0, 0, 0);
    }
    __syncthreads();   // all af reads done -> smT (alias of smA) may be written

    // ---- epilogue: two half-passes through smT for coalesced bf16 stores ----
    // FULLY unrolled so acc[] stays statically indexed (earlier session: a
    // runtime-indexed acc spilled to scratch -> 1.6GB HBM traffic).
#pragma unroll
    for (int h = 0; h < 2; ++h) {
#pragma unroll
      for (int mt2 = 0; mt2 < 2; ++mt2) {
        const int mt = 2 * h + mt2;
#pragma unroll
        for (int nt = 0; nt < 4; ++nt)
#pragma unroll
          for (int i = 0; i < 4; ++i) {
            int mrow = mt2 * 16 + lg * 4 + i;
            int n = wave * 64 + nt * 16 + lr;
            smT[mrow * 520 + n] = f2b(acc[mt][nt][i] + b1v[nt]);
          }
      }
      __syncthreads();
      int m = m0 + h * 32 + rs;
      if (m < n_nodes) {
#pragma unroll
        for (int j = 0; j < 4; ++j) {
          int c = cs + j * 128;
          *(bfx8*)(PQ + (size_t)m * 512 + c) = *(const bfx8*)&smT[rs * 520 + c];
        }
      }
      __syncthreads();
    }
  }
}

// ---------------- edge kernel: h1=relu(P[src]+Q[dst]); h2=relu(h1@W2^T+b2); out=h2@w3+b3 --
// persistent, 4 waves/block; wave w owns n in [w*64, w*64+64); W2 frags live in registers.
// ROUND-0 PROVEN STRUCTURE (92us). b1 is pre-folded into the P half of PQ by
// k_node, so the fuse is just relu(P+Q). Third barrier removed (smH only read
// in GEMM before the epilogue sync; smS(t+1) writes ordered by fuse-sync(t+1)).
//
// OCCUPANCY MODEL (round-3): arch regs = VGPR(128) + AGPRs -> 129..256 bucket
// -> 8 waves/CU = 2 blocks/CU regardless of grid (512 and 1024 both ~20.5%).
// DO NOT tighten __launch_bounds__ past (256,2): (256,4) forced VGPR=64 and
// spilled bw[] (WRITE 7.3->137MB, 92->180us).
// DO NOT add a 64-reg pv/qv prefetch: round-4 measured it spills (live set
// bw128+pv/qv64+acc64+af16 > 256) -> WRITE 13->57MB, FETCH 163->316MB, 148us.
__launch_bounds__(256, 2)
__global__ void k_edge(const unsigned short* __restrict__ PQ,
                       const int* __restrict__ src, const int* __restrict__ dst,
                       const unsigned short* __restrict__ W2b,
                       const float* __restrict__ b2, const float* __restrict__ W3,
                       const float* __restrict__ b3, float* __restrict__ out,
                       int E, int ntiles) {
  __shared__ __align__(16) short smH[64 * 264];   // stride 264 (pad 8) -> 16B-aligned rows
  __shared__ float smS[4][64];
  const int tid = threadIdx.x;
  const int wave = tid >> 6, lane = tid & 63;
  const int lr = lane & 15, lg = lane >> 4;

  // W2 fragments (this wave's 64 N rows, full K=256): 4 n-tiles x 8 k-steps
  bfx8 bw[4][8];
  float b2v[4], w3v[4];
#pragma unroll
  for (int nt = 0; nt < 4; ++nt) {
    int n = wave * 64 + nt * 16 + lr;
    b2v[nt] = b2[n];
    w3v[nt] = W3[n];
#pragma unroll
    for (int ks = 0; ks < 8; ++ks)
      bw[nt][ks] = *(const bfx8*)(W2b + n * 256 + ks * 32 + lg * 8);
  }
  const float b3v = b3[0];

  for (int tile = blockIdx.x; tile < ntiles; tile += gridDim.x) {
    const int base = tile * E_TILE;
    // gather + fuse layer1: h1 = relu(P'[src]+Q[dst]) -> smH bf16  (b1 already in P')
    {
      int r = tid >> 2;
      int e = base + r;
      if (e < E) {
        int s = src[e], d = dst[e];
        const unsigned short* ps = PQ + (size_t)s * 512;
        const unsigned short* pd = PQ + (size_t)d * 512 + 256;
#pragma unroll
        for (int it = 0; it < 8; ++it) {
          int c = (tid & 3) * 8 + it * 32;
          bfx8 pv = *(const bfx8*)(ps + c);
          bfx8 qv = *(const bfx8*)(pd + c);
          bfx8 o;
#pragma unroll
          for (int j = 0; j < 8; ++j)
            o[j] = f2b(relu(b2f(pv[j]) + b2f(qv[j])));
          *(bfx8*)&smH[r * 264 + c] = o;
        }
      } else {
        bfx8 z = (bfx8){0,0,0,0,0,0,0,0};
#pragma unroll
        for (int it = 0; it < 8; ++it) {
          int c = (tid & 3) * 8 + it * 32;
          *(bfx8*)&smH[r * 264 + c] = z;
        }
      }
    }
    __syncthreads();

    // layer2 GEMM: 64M x 64N per wave, K=256
    fx4 acc[4][4] = {};
#pragma unroll
    for (int ks = 0; ks < 8; ++ks) {
      bfx8 af[4];
#pragma unroll
      for (int mt = 0; mt < 4; ++mt)
        af[mt] = *(const bfx8*)&smH[(mt * 16 + lr) * 264 + ks * 32 + lg * 8];
#pragma unroll
      for (int nt = 0; nt < 4; ++nt)
#pragma unroll
        for (int mt = 0; mt < 4; ++mt)
          acc[mt][nt] = __builtin_amdgcn_mfma_f32_16x16x32_bf16(af[mt], bw[nt][ks], acc[mt][nt], 0, 0, 0);
    }

    // epilogue: relu(acc+b2) dot w3, reduce over this wave's 64 n via shfl within 16-groups
#pragma unroll
    for (int mt = 0; mt < 4; ++mt)
#pragma unroll
      for (int i = 0; i < 4; ++i) {
        float p = 0.f;
#pragma unroll
        for (int nt = 0; nt < 4; ++nt)
          p += relu(acc[mt][nt][i] + b2v[nt]) * w3v[nt];
        p += __shfl_xor(p, 1);
        p += __shfl_xor(p, 2);
        p += __shfl_xor(p, 4);
        p += __shfl_xor(p, 8);
        if (lr == 0) smS[wave][mt * 16 + lg * 4 + i] = p;
      }
    __syncthreads();
    if (tid < 64) {
      int e = base + tid;
      if (e < E) out[e] = smS[0][tid] + smS[1][tid] + smS[2][tid] + smS[3][tid] + b3v;
    }
    // no trailing sync needed: smH reads all precede the epilogue sync, and
    // smS(t+1) writes are ordered after out(t) by the next fuse-sync.
  }
}

// ---------------- fallback (if ws too small): naive fp32, 1 edge per wave ----------------
__global__ void k_fallback(const float* __restrict__ x, const int* __restrict__ src,
                           const int* __restrict__ dst, const float* __restrict__ W1,
                           const float* __restrict__ b1, const float* __restrict__ W2,
                           const float* __restrict__ b2, const float* __restrict__ W3,
                           const float* __restrict__ b3, float* __restrict__ out, int E) {
  __shared__ float smF[4][512];
  __shared__ float smG[4][256];
  int wave = threadIdx.x >> 6, lane = threadIdx.x & 63;
  int e = blockIdx.x * 4 + wave;
  bool valid = e < E;
  int ec = valid ? e : 0;
  int s = src[ec], d = dst[ec];
  for (int j = 0; j < 8; ++j) {
    int k = lane * 8 + j;
    smF[wave][k] = (k < 256) ? x[(size_t)s * 256 + k] : x[(size_t)d * 256 + k - 256];
  }
  __syncthreads();
  for (int t = 0; t < 4; ++t) {
    int n = lane + t * 64;
    float a = b1[n];
    for (int k = 0; k < 512; ++k) a += smF[wave][k] * W1[n * 512 + k];
    smG[wave][n] = relu(a);
  }
  __syncthreads();
  float p = 0.f;
  for (int t = 0; t < 4; ++t) {
    int n = lane + t * 64;
    float a = b2[n];
    for (int k = 0; k < 256; ++k) a += smG[wave][k] * W2[n * 256 + k];
    p += relu(a) * W3[n];
  }
  for (int m = 1; m < 64; m <<= 1) p += __shfl_xor(p, m);
  if (lane == 0 && valid) out[e] = p + b3[0];
}

extern "C" void kernel_launch(void* const* d_in, const int* in_sizes, int n_in,
                              void* d_out, int out_size, void* d_ws, size_t ws_size,
                              hipStream_t stream) {
  const float* x  = (const float*)d_in[0];
  const int*   src = (const int*)d_in[1];
  const int*   dst = (const int*)d_in[2];
  const float* W1 = (const float*)d_in[3];
  const float* b1 = (const float*)d_in[4];
  const float* W2 = (const float*)d_in[5];
  const float* b2 = (const float*)d_in[6];
  const float* W3 = (const float*)d_in[7];
  const float* b3 = (const float*)d_in[8];
  float* out = (float*)d_out;

  const int E = in_sizes[1];
  const int n_nodes = in_sizes[0] / 256;

  const size_t offB1 = 0;
  const size_t offW2 = (size_t)512 * 256 * 2;                 // 262144
  const size_t offPQ = offW2 + (size_t)256 * 256 * 2;         // 393216
  const size_t need = offPQ + (size_t)n_nodes * 512 * 2;      // ~51.6 MB

  if (ws_size >= need) {
    unsigned short* B1  = (unsigned short*)((char*)d_ws + offB1);
    unsigned short* W2b = (unsigned short*)((char*)d_ws + offW2);
    unsigned short* PQ  = (unsigned short*)((char*)d_ws + offPQ);
    k_prep<<<768, 256, 0, stream>>>(W1, W2, B1, W2b);
    const int ntiles_node = (n_nodes + 63) / 64;
    k_node<<<256, 512, 0, stream>>>(x, B1, b1, PQ, n_nodes, ntiles_node);
    const int ntiles = (E + E_TILE - 1) / E_TILE;
    k_edge<<<512, 256, 0, stream>>>(PQ, src, dst, W2b, b2, W3, b3, out, E, ntiles);
  } else {
    k_fallback<<<(E + 3) / 4, 256, 0, stream>>>(x, src, dst, W1, b1, W2, b2, W3, b3, out, E);
  }
}